// Round 4
// baseline (708.678 us; speedup 1.0000x reference)
//
#include <hip/hip_runtime.h>
#include <hip/hip_bf16.h>
#include <cstdint>

typedef __hip_bfloat16 bf16;
typedef short bf16x8 __attribute__((ext_vector_type(8)));
typedef float f32x4 __attribute__((ext_vector_type(4)));

#define RATIO 0.0625f
#define EPS_F 0.001f

__device__ __forceinline__ void unpack8(uint4 u, float* f) {
  f[0] = __uint_as_float(u.x << 16); f[1] = __uint_as_float(u.x & 0xffff0000u);
  f[2] = __uint_as_float(u.y << 16); f[3] = __uint_as_float(u.y & 0xffff0000u);
  f[4] = __uint_as_float(u.z << 16); f[5] = __uint_as_float(u.z & 0xffff0000u);
  f[6] = __uint_as_float(u.w << 16); f[7] = __uint_as_float(u.w & 0xffff0000u);
}

__device__ __forceinline__ unsigned short f2bf(float f) {
  unsigned int u = __float_as_uint(f);
  unsigned int r = (u + 0x7fffu + ((u >> 16) & 1u)) >> 16;
  return (unsigned short)r;
}

// async global->LDS, 16B per lane. LDS dest = wave-uniform base + lane*16.
// Global source IS per-lane -> swizzled LDS via pre-swizzled source (rule #21).
__device__ __forceinline__ void gload_lds16(const void* g, void* l) {
  __builtin_amdgcn_global_load_lds(
      (const __attribute__((address_space(1))) void*)(uintptr_t)g,
      (__attribute__((address_space(3))) void*)(uintptr_t)l, 16, 0, 0);
}

__global__ void zero_kernel(float* __restrict__ p, int n) {
  int i = blockIdx.x * 256 + threadIdx.x;
  if (i < n) p[i] = 0.f;
}

// fp32 -> bf16 conversion, 4 elems/thread. n must be a multiple of 4.
__global__ void conv_kernel(const float* __restrict__ src,
                            unsigned short* __restrict__ dst, long n) {
  long i = ((long)blockIdx.x * 256 + threadIdx.x) * 4;
  if (i < n) {
    float4 v = *(const float4*)(src + i);
    ushort4 o;
    o.x = f2bf(v.x); o.y = f2bf(v.y); o.z = f2bf(v.z); o.w = f2bf(v.w);
    *(ushort4*)(dst + i) = o;
  }
}

// ---------------------------------------------------------------------------
// GEMM helpers (Q is a template param so all acc indices are compile-time).
__device__ __forceinline__ void ds_read_B8(const short* Bb, int rB0, int l16,
                                           int quad, bf16x8 bfr[4][2]) {
  const int sw = l16 & 7;
#pragma unroll
  for (int ni = 0; ni < 4; ++ni)
#pragma unroll
    for (int ks = 0; ks < 2; ++ks)
      bfr[ni][ks] = *(const bf16x8*)
          &Bb[(rB0 + ni * 16 + l16) * 64 + (((ks * 4 + quad) ^ sw) * 8)];
}

template <int Q>
__device__ __forceinline__ void ds_read_A4(const short* Ab, int l16, int quad,
                                           bf16x8 af[2][2]) {
  const int sw = l16 & 7;
#pragma unroll
  for (int i = 0; i < 2; ++i)
#pragma unroll
    for (int ks = 0; ks < 2; ++ks)
      af[i][ks] = *(const bf16x8*)
          &Ab[((Q * 2 + i) * 16 + l16) * 64 + (((ks * 4 + quad) ^ sw) * 8)];
}

template <int Q>
__device__ __forceinline__ void mfma16(f32x4 acc[8][4], bf16x8 af[2][2],
                                       bf16x8 bfr[4][2]) {
#pragma unroll
  for (int i = 0; i < 2; ++i)
#pragma unroll
    for (int ni = 0; ni < 4; ++ni)
#pragma unroll
      for (int ks = 0; ks < 2; ++ks)
        acc[Q * 2 + i][ni] = __builtin_amdgcn_mfma_f32_16x16x32_bf16(
            af[i][ks], bfr[ni][ks], acc[Q * 2 + i][ni], 0, 0, 0);
}

// ---------------------------------------------------------------------------
// C[m][n] = sum_k A[m][k] * Bt[n][k] + bias[n]. A,Bt bf16; bias fp32.
// 256x256 tile, 512 thr = 8 waves (2M x 4N), BK=64, 4 phases/K-tile.
// Whole-buffer double-buffering: iteration it reads buf d=it&1 (tile it) and
// stages tile it+1 into buf nd (2 gloads/phase, order B0B1 B2B3 A0A1 A2A3).
// Counted vmcnt per phase (oldest-first bookkeeping): steady 4/5/6/3,
// last iter 2/1/0/-. B held in regs from phase 0 (A-quadrant reads only after).
// LDS swizzle (T2): 16B unit u within 128x64 half holds linear unit
// u ^ ((u>>3)&7); staged via pre-swizzled global source, read XORs same.
// M,N multiples of 256, K multiple of 64, K/64 >= 2.
template <bool OUT_F32>
__global__ __launch_bounds__(512, 2) void gemm_bt_kernel(
    const bf16* __restrict__ A, const bf16* __restrict__ Bt,
    const float* __restrict__ bias, void* __restrict__ Cout,
    int Ndim, int Kdim)
{
  __shared__ short lds[65536];  // A0 [0,16K) A1 [16K,32K) B0 [32K,48K) B1 [48K,64K) shorts
  const int tid = threadIdx.x;
  const int lane = tid & 63;
  const int w = tid >> 6;
  const int wr = w >> 2;        // 0..1  (M warps)
  const int wc = w & 3;         // 0..3  (N warps)
  const int quad = lane >> 4, l16 = lane & 15;

  // bijective XCD-aware block swizzle (m204)
  int gx = gridDim.x;
  int nwg = gx * gridDim.y;
  int flat = blockIdx.y * gx + blockIdx.x;
  int qq = nwg >> 3, rr = nwg & 7;
  int xcd = flat & 7, sub = flat >> 3;
  int wg = (xcd < rr ? xcd * (qq + 1) : rr * (qq + 1) + (xcd - rr) * qq) + sub;
  long m0 = (long)(wg / gx) * 256;
  long n0 = (long)(wg % gx) * 256;

  // staging geometry. Source colseg pre-swizzled: (lane&7) ^ ((lane>>3)&7).
  const int r8 = lane >> 3;
  const int csw = ((lane & 7) ^ (r8 & 7)) * 8;
  // A quadrant qa (rows qa*32..+31 of each 128-half): waves 0-3 -> half0,
  // waves 4-7 -> half1. One gload per wave per quadrant.
  const bf16* gAs = A + (m0 + (w >> 2) * 128 + (w & 3) * 8 + r8) * (long)Kdim + csw;
  // B chunk j (rows j*64..+63): all 8 waves, one gload per wave per chunk.
  const bf16* gBs = Bt + (n0 + w * 8 + r8) * (long)Kdim + csw;
  short* dA = &lds[(w >> 2) * 8192 + (w & 3) * 512];   // + nd*16384 + qa*2048
  short* dB = &lds[32768 + w * 512];                   // + nd*16384 + j*4096
  const long kb64 = 64L * Kdim;   // B chunk row stride
  const long ka32 = 32L * Kdim;   // A quadrant row stride

  f32x4 acc[8][4];
#pragma unroll
  for (int i = 0; i < 8; i++)
#pragma unroll
    for (int j = 0; j < 4; j++)
      acc[i][j] = (f32x4){0.f, 0.f, 0.f, 0.f};

  const int NIT = Kdim >> 6;

  // prologue: stage tile 0 into buf 0 (order B0..B3, A0..A3)
#pragma unroll
  for (int j = 0; j < 4; ++j) gload_lds16(gBs + j * kb64, dB + j * 4096);
#pragma unroll
  for (int qa = 0; qa < 4; ++qa) gload_lds16(gAs + qa * ka32, dA + qa * 2048);
  asm volatile("s_waitcnt vmcnt(3)" ::: "memory");  // B*,A0 resident
  __builtin_amdgcn_s_barrier();

  bf16x8 bfr[4][2], af[2][2];

  for (int it = 0; it < NIT; ++it) {
    const int d = it & 1, nd = d ^ 1;
    const bool pf = (it < NIT - 1);
    const long kq1 = (long)(it + 1) * 64;
    const short* Ab = &lds[d * 16384 + wr * 8192];
    const short* Bb = &lds[32768 + d * 16384 + (wc >> 1) * 8192];
    const int rB0 = (wc & 1) * 64;
    short* dAn = dA + nd * 16384;
    short* dBn = dB + nd * 16384;

    // ---- phase 0: read all B + A q0; stage B0',B1' ----
    ds_read_B8(Bb, rB0, l16, quad, bfr);
    ds_read_A4<0>(Ab, l16, quad, af);
    if (pf) {
      gload_lds16(gBs + kq1, dBn);
      gload_lds16(gBs + kb64 + kq1, dBn + 4096);
      asm volatile("s_waitcnt vmcnt(4)" ::: "memory");   // A1 resident
    } else {
      asm volatile("s_waitcnt vmcnt(2)" ::: "memory");
    }
    asm volatile("s_waitcnt lgkmcnt(8)" ::: "memory");
    __builtin_amdgcn_s_barrier();
    asm volatile("s_waitcnt lgkmcnt(0)" ::: "memory");
    __builtin_amdgcn_sched_barrier(0);
    __builtin_amdgcn_s_setprio(1);
    mfma16<0>(acc, af, bfr);
    __builtin_amdgcn_s_setprio(0);
    __builtin_amdgcn_s_barrier();

    // ---- phase 1: read A q1; stage B2',B3' ----
    ds_read_A4<1>(Ab, l16, quad, af);
    if (pf) {
      gload_lds16(gBs + 2 * kb64 + kq1, dBn + 8192);
      gload_lds16(gBs + 3 * kb64 + kq1, dBn + 12288);
      asm volatile("s_waitcnt vmcnt(5)" ::: "memory");   // A2 resident
    } else {
      asm volatile("s_waitcnt vmcnt(1)" ::: "memory");
    }
    __builtin_amdgcn_s_barrier();
    asm volatile("s_waitcnt lgkmcnt(0)" ::: "memory");
    __builtin_amdgcn_sched_barrier(0);
    __builtin_amdgcn_s_setprio(1);
    mfma16<1>(acc, af, bfr);
    __builtin_amdgcn_s_setprio(0);
    __builtin_amdgcn_s_barrier();

    // ---- phase 2: read A q2; stage A0',A1' ----
    ds_read_A4<2>(Ab, l16, quad, af);
    if (pf) {
      gload_lds16(gAs + kq1, dAn);
      gload_lds16(gAs + ka32 + kq1, dAn + 2048);
      asm volatile("s_waitcnt vmcnt(6)" ::: "memory");   // A3 resident
    } else {
      asm volatile("s_waitcnt vmcnt(0)" ::: "memory");
    }
    __builtin_amdgcn_s_barrier();
    asm volatile("s_waitcnt lgkmcnt(0)" ::: "memory");
    __builtin_amdgcn_sched_barrier(0);
    __builtin_amdgcn_s_setprio(1);
    mfma16<2>(acc, af, bfr);
    __builtin_amdgcn_s_setprio(0);
    __builtin_amdgcn_s_barrier();

    // ---- phase 3: read A q3; stage A2',A3' ----
    ds_read_A4<3>(Ab, l16, quad, af);
    if (pf) {
      gload_lds16(gAs + 2 * ka32 + kq1, dAn + 4096);
      gload_lds16(gAs + 3 * ka32 + kq1, dAn + 6144);
      asm volatile("s_waitcnt vmcnt(3)" ::: "memory");   // B'*,A0' resident
    }
    __builtin_amdgcn_s_barrier();
    asm volatile("s_waitcnt lgkmcnt(0)" ::: "memory");
    __builtin_amdgcn_sched_barrier(0);
    __builtin_amdgcn_s_setprio(1);
    mfma16<3>(acc, af, bfr);
    __builtin_amdgcn_s_setprio(0);
    __builtin_amdgcn_s_barrier();
  }

  // epilogue
#pragma unroll
  for (int ni = 0; ni < 4; ++ni) {
    long col = n0 + wc * 64 + ni * 16 + l16;
    float bv = bias[col];
#pragma unroll
    for (int mi = 0; mi < 8; ++mi) {
      long row = m0 + wr * 128 + mi * 16 + quad * 4;
#pragma unroll
      for (int r = 0; r < 4; ++r) {
        float val = acc[mi][ni][r] + bv;
        if (OUT_F32)
          ((float*)Cout)[(row + r) * Ndim + col] = val;
        else
          ((bf16*)Cout)[(row + r) * Ndim + col] = __float2bfloat16(val);
      }
    }
  }
}

// ---------------------------------------------------------------------------
// kv_mfma: per (b,h) x L-chunk(512): kv^ acc via MFMA.
// MFMA1k: S[l][m] = sum_d k[l][d] pm[m][d]  (C: row=l, col=m)
// kp3[m][l] = bf16(relu(S*ratio)+eps)
// MFMA2k: kv[m][d] += sum_l kp3[m][l] * v[l][d]  (C: row=m, col=d)
// atomicAdd into kvbuf[bh][d][m] fp32; ksum[bh][m] via LDS row sums.
__global__ __launch_bounds__(256) void kv_mfma_kernel(
    const bf16* __restrict__ qkv, const bf16* __restrict__ pmb,
    float* __restrict__ kvbuf, float* __restrict__ ksumb)
{
  int bh = blockIdx.x;
  int b = bh / 12, h = bh % 12;
  int l0 = blockIdx.y * 512;
  int tid = threadIdx.x, lane = tid & 63, w = tid >> 6;
  int quad = lane >> 4, l16 = lane & 15;

  __shared__ short k_lds[64 * 72];
  __shared__ short v_lds[64 * 72];   // stored swizzled: [l][d ^ (((l>>3)&3)<<4)]
  __shared__ short kp3[256 * 72];    // [m][l]

  f32x4 kvacc[4][4];
#pragma unroll
  for (int mt = 0; mt < 4; mt++)
#pragma unroll
    for (int dt = 0; dt < 4; dt++)
      kvacc[mt][dt] = (f32x4){0.f, 0.f, 0.f, 0.f};
  float ksum_r = 0.f;

  int srow = tid >> 2, sseg = (tid & 3) * 8;
  int swz = ((srow >> 3) & 3) << 4;

  for (int tile = 0; tile < 8; tile++) {
    long gr = ((long)(b * 4096 + l0 + tile * 64 + srow)) * 2304 + h * 64;
    uint4 kk0 = *(const uint4*)(qkv + gr + 768 + sseg);
    uint4 kk1 = *(const uint4*)(qkv + gr + 768 + sseg + 32);
    uint4 vv0 = *(const uint4*)(qkv + gr + 1536 + sseg);
    uint4 vv1 = *(const uint4*)(qkv + gr + 1536 + sseg + 32);
    __syncthreads();   // protect LDS from previous iteration readers
    *(uint4*)&k_lds[srow * 72 + sseg] = kk0;
    *(uint4*)&k_lds[srow * 72 + sseg + 32] = kk1;
    *(uint4*)&v_lds[srow * 72 + (sseg ^ swz)] = vv0;
    *(uint4*)&v_lds[srow * 72 + ((sseg + 32) ^ swz)] = vv1;
    __syncthreads();

    // MFMA1k
    bf16x8 af[4][2], bpm[4][2];
#pragma unroll
    for (int lt = 0; lt < 4; lt++)
#pragma unroll
      for (int ks = 0; ks < 2; ks++)
        af[lt][ks] = *(const bf16x8*)&k_lds[(lt * 16 + l16) * 72 + ks * 32 + quad * 8];
#pragma unroll
    for (int mt = 0; mt < 4; mt++)
#pragma unroll
      for (int ks = 0; ks < 2; ks++)
        bpm[mt][ks] = *(const bf16x8*)(pmb + (w * 64 + mt * 16 + l16) * 64 + ks * 32 + quad * 8);

#pragma unroll
    for (int lt = 0; lt < 4; lt++)
#pragma unroll
      for (int mt = 0; mt < 4; mt++) {
        f32x4 s = (f32x4){0.f, 0.f, 0.f, 0.f};
        s = __builtin_amdgcn_mfma_f32_16x16x32_bf16(af[lt][0], bpm[mt][0], s, 0, 0, 0);
        s = __builtin_amdgcn_mfma_f32_16x16x32_bf16(af[lt][1], bpm[mt][1], s, 0, 0, 0);
        ushort4 pk;
        pk.x = f2bf(fmaxf(s[0] * RATIO, 0.f) + EPS_F);
        pk.y = f2bf(fmaxf(s[1] * RATIO, 0.f) + EPS_F);
        pk.z = f2bf(fmaxf(s[2] * RATIO, 0.f) + EPS_F);
        pk.w = f2bf(fmaxf(s[3] * RATIO, 0.f) + EPS_F);
        // rows l = lt*16 + quad*4 + r, col m = w*64 + mt*16 + l16
        *(ushort4*)&kp3[(w * 64 + mt * 16 + l16) * 72 + lt * 16 + quad * 4] = pk;
      }
    __syncthreads();

    // ksum for feature row m = tid
#pragma unroll
    for (int j8 = 0; j8 < 8; j8++) {
      uint4 u = *(const uint4*)&kp3[tid * 72 + j8 * 8];
      float f[8]; unpack8(u, f);
      ksum_r += ((f[0] + f[1]) + (f[2] + f[3])) + ((f[4] + f[5]) + (f[6] + f[7]));
    }

    // MFMA2k
#pragma unroll
    for (int ls = 0; ls < 2; ls++) {
      bf16x8 a2[4];
#pragma unroll
      for (int mt = 0; mt < 4; mt++)
        a2[mt] = *(const bf16x8*)&kp3[(w * 64 + mt * 16 + l16) * 72 + ls * 32 + quad * 8];
#pragma unroll
      for (int dt = 0; dt < 4; dt++) {
        bf16x8 b2;
        int dcol = (dt * 16 + l16) ^ (quad << 4);
#pragma unroll
        for (int jj = 0; jj < 8; jj++)
          b2[jj] = v_lds[(ls * 32 + quad * 8 + jj) * 72 + dcol];
#pragma unroll
        for (int mt = 0; mt < 4; mt++)
          kvacc[mt][dt] = __builtin_amdgcn_mfma_f32_16x16x32_bf16(a2[mt], b2, kvacc[mt][dt], 0, 0, 0);
      }
    }
  }

#pragma unroll
  for (int mt = 0; mt < 4; mt++)
#pragma unroll
    for (int dt = 0; dt < 4; dt++)
#pragma unroll
      for (int r = 0; r < 4; r++)
        atomicAdd(kvbuf + ((long)bh * 64 + dt * 16 + l16) * 256 + w * 64 + mt * 16 + quad * 4 + r,
                  kvacc[mt][dt][r]);
  atomicAdd(ksumb + bh * 256 + tid, ksum_r);
}

// ---------------------------------------------------------------------------
// attn_mfma: per (b,h) x 64 L-rows.
// MFMA1: S[m][l] = sum_d pm[m][d] q[l][d]  (C: row=m, col=l)
// qp2[l][m] = bf16(relu(S*ratio)+eps)
// den[l] = sum_m qp2[l][m]*ksum[m]  (thread-parallel + LDS reduce)
// MFMA2: num[l][d] = sum_m qp2[l][m] * kvt[d][m]  (C: row=l, col=d)
// kvt B-fragments read DIRECT from global (L2-hot: 32KB/bh shared by 64 blocks).
__global__ __launch_bounds__(256) void attn_mfma_kernel(
    const bf16* __restrict__ qkv, const bf16* __restrict__ pmb,
    const bf16* __restrict__ kvtb, const float* __restrict__ ksumb,
    bf16* __restrict__ attn)
{
  int bh = blockIdx.x;
  int b = bh / 12, h = bh % 12;
  int l0 = blockIdx.y * 64;
  int tid = threadIdx.x, lane = tid & 63, w = tid >> 6;
  int quad = lane >> 4, l16 = lane & 15;

  __shared__ short q_lds[64 * 72];
  __shared__ short qp2[64 * 264];     // [l][m]
  __shared__ float ksum_lds[256];
  __shared__ float den_part[4][64];

  {
    int srow = tid >> 2, sseg = (tid & 3) * 8;
    long gr = ((long)(b * 4096 + l0 + srow)) * 2304 + h * 64;
    *(uint4*)&q_lds[srow * 72 + sseg]      = *(const uint4*)(qkv + gr + sseg);
    *(uint4*)&q_lds[srow * 72 + sseg + 32] = *(const uint4*)(qkv + gr + sseg + 32);
  }
  ksum_lds[tid] = ksumb[bh * 256 + tid];
  __syncthreads();

  // MFMA1
  {
    bf16x8 apm[4][2], bq[4][2];
#pragma unroll
    for (int mt = 0; mt < 4; mt++)
#pragma unroll
      for (int ks = 0; ks < 2; ks++)
        apm[mt][ks] = *(const bf16x8*)(pmb + (w * 64 + mt * 16 + l16) * 64 + ks * 32 + quad * 8);
#pragma unroll
    for (int lt = 0; lt < 4; lt++)
#pragma unroll
      for (int ks = 0; ks < 2; ks++)
        bq[lt][ks] = *(const bf16x8*)&q_lds[(lt * 16 + l16) * 72 + ks * 32 + quad * 8];

#pragma unroll
    for (int mt = 0; mt < 4; mt++)
#pragma unroll
      for (int lt = 0; lt < 4; lt++) {
        f32x4 s = (f32x4){0.f, 0.f, 0.f, 0.f};
        s = __builtin_amdgcn_mfma_f32_16x16x32_bf16(apm[mt][0], bq[lt][0], s, 0, 0, 0);
        s = __builtin_amdgcn_mfma_f32_16x16x32_bf16(apm[mt][1], bq[lt][1], s, 0, 0, 0);
        ushort4 pk;
        pk.x = f2bf(fmaxf(s[0] * RATIO, 0.f) + EPS_F);
        pk.y = f2bf(fmaxf(s[1] * RATIO, 0.f) + EPS_F);
        pk.z = f2bf(fmaxf(s[2] * RATIO, 0.f) + EPS_F);
        pk.w = f2bf(fmaxf(s[3] * RATIO, 0.f) + EPS_F);
        // row l = lt*16 + l16, cols m = w*64 + mt*16 + quad*4 + r
        *(ushort4*)&qp2[(lt * 16 + l16) * 264 + w * 64 + mt * 16 + quad * 4] = pk;
      }
  }
  __syncthreads();

  // den partials
  {
    int l = tid & 63, Q = tid >> 6;
    float dp = 0.f;
#pragma unroll
    for (int j8 = 0; j8 < 8; j8++) {
      uint4 u = *(const uint4*)&qp2[l * 264 + Q * 64 + j8 * 8];
      float f[8]; unpack8(u, f);
#pragma unroll
      for (int i = 0; i < 8; i++) dp += f[i] * ksum_lds[Q * 64 + j8 * 8 + i];
    }
    den_part[Q][l] = dp;
  }

  // MFMA2: wave strip l = w*16..w*16+15; kvt B-frags direct from global.
  const bf16* kvg = kvtb + (long)bh * 16384;
  f32x4 o[4];
#pragma unroll
  for (int dt = 0; dt < 4; dt++) o[dt] = (f32x4){0.f, 0.f, 0.f, 0.f};
#pragma unroll
  for (int ms = 0; ms < 8; ms++) {
    bf16x8 aq = *(const bf16x8*)&qp2[(w * 16 + l16) * 264 + ms * 32 + quad * 8];
#pragma unroll
    for (int dt = 0; dt < 4; dt++) {
      bf16x8 bk = *(const bf16x8*)(kvg + (dt * 16 + l16) * 256 + ms * 32 + quad * 8);
      o[dt] = __builtin_amdgcn_mfma_f32_16x16x32_bf16(aq, bk, o[dt], 0, 0, 0);
    }
  }
  __syncthreads();

  float rden[4];
#pragma unroll
  for (int r = 0; r < 4; r++) {
    int l = w * 16 + quad * 4 + r;
    rden[r] = 1.f / (den_part[0][l] + den_part[1][l] + den_part[2][l] + den_part[3][l]);
  }
#pragma unroll
  for (int dt = 0; dt < 4; dt++)
#pragma unroll
    for (int r = 0; r < 4; r++) {
      int l = w * 16 + quad * 4 + r;
      attn[((long)(b * 4096 + l0 + l)) * 768 + h * 64 + dt * 16 + l16] =
          __float2bfloat16(o[dt][r] * rden[r]);
    }
}

extern "C" void kernel_launch(void* const* d_in, const int* in_sizes, int n_in,
                              void* d_out, int out_size, void* d_ws, size_t ws_size,
                              hipStream_t stream)
{
  const float* x      = (const float*)d_in[0];
  const float* qkv_w  = (const float*)d_in[1];
  const float* qkv_b  = (const float*)d_in[2];
  const float* proj_w = (const float*)d_in[3];
  const float* proj_b = (const float*)d_in[4];
  const float* pmat   = (const float*)d_in[5];
  float* out = (float*)d_out;

  // ws layout (212,434,944 B total):
  //   qkv   bf16  [0, 150994944)
  //   xbuf  bf16  [150994944, 201326592)   (attn aliases; disjoint lifetime)
  //   kvbuf fp32  [201326592, 207618048)   96*64*256
  //   ksumb fp32  [207618048, 207716352)   96*256
  //   wqkv  bf16  [207716352, 211255296)   dead after gemm1; kvtb+pmb alias in
  //     kvtb bf16 [207716352, 210862080)   96*64*256
  //     pmb  bf16 [210862080, 210894848)   256*64
  //   wproj bf16  [211255296, 212434944)
  char* ws = (char*)d_ws;
  bf16*  qkv   = (bf16*)ws;
  bf16*  xbuf  = (bf16*)(ws + 150994944);
  bf16*  attn  = xbuf;
  float* kvbuf = (float*)(ws + 201326592);
  float* ksumb = (float*)(ws + 207618048);
  bf16*  wqkv  = (bf16*)(ws + 207716352);
  bf16*  kvtb  = (bf16*)(ws + 207716352);
  bf16*  pmb   = (bf16*)(ws + 210862080);
  bf16*  wproj = (bf16*)(ws + 211255296);

  int nz = 96 * 64 * 256 + 96 * 256;  // kvbuf + ksumb (contiguous)
  zero_kernel<<<dim3((nz + 255) / 256), 256, 0, stream>>>(kvbuf, nz);

  conv_kernel<<<dim3(25165824 / 1024), 256, 0, stream>>>(x, (unsigned short*)xbuf, 25165824L);
  conv_kernel<<<dim3(1769472 / 1024), 256, 0, stream>>>(qkv_w, (unsigned short*)wqkv, 1769472L);
  conv_kernel<<<dim3(589824 / 1024), 256, 0, stream>>>(proj_w, (unsigned short*)wproj, 589824L);

  // QKV projection: (32768 x 768) @ (2304 x 768)^T -> bf16 qkv
  gemm_bt_kernel<false><<<dim3(2304 / 256, 32768 / 256), 512, 0, stream>>>(
      xbuf, wqkv, qkv_b, qkv, 2304, 768);

  // pm -> bf16 (region overlaps wqkv tail: must be after gemm1)
  conv_kernel<<<dim3(16384 / 1024), 256, 0, stream>>>(pmat, (unsigned short*)pmb, 16384L);

  // kv + ksum (MFMA)
  kv_mfma_kernel<<<dim3(96, 8), 256, 0, stream>>>(qkv, pmb, kvbuf, ksumb);

  // kvbuf fp32 -> kvtb bf16 (overlaps wqkv front: after gemm1; after kv_mfma)
  conv_kernel<<<dim3(1572864 / 1024), 256, 0, stream>>>(kvbuf, (unsigned short*)kvtb, 1572864L);

  // q features + num/den + normalize -> bf16 attn (MFMA)
  attn_mfma_kernel<<<dim3(96, 64), 256, 0, stream>>>(qkv, pmb, kvtb, ksumb, attn);

  // output projection: (32768 x 768) @ (768 x 768)^T -> fp32 out
  gemm_bt_kernel<true><<<dim3(768 / 256, 32768 / 256), 512, 0, stream>>>(
      attn, wproj, proj_b, out, 768, 768);
}

// Round 5
// 560.999 us; speedup vs baseline: 1.2632x; 1.2632x over previous
//
#include <hip/hip_runtime.h>
#include <hip/hip_bf16.h>
#include <cstdint>

typedef __hip_bfloat16 bf16;
typedef short bf16x8 __attribute__((ext_vector_type(8)));
typedef float f32x4 __attribute__((ext_vector_type(4)));

#define RATIO 0.0625f
#define EPS_F 0.001f

__device__ __forceinline__ void unpack8(uint4 u, float* f) {
  f[0] = __uint_as_float(u.x << 16); f[1] = __uint_as_float(u.x & 0xffff0000u);
  f[2] = __uint_as_float(u.y << 16); f[3] = __uint_as_float(u.y & 0xffff0000u);
  f[4] = __uint_as_float(u.z << 16); f[5] = __uint_as_float(u.z & 0xffff0000u);
  f[6] = __uint_as_float(u.w << 16); f[7] = __uint_as_float(u.w & 0xffff0000u);
}

__device__ __forceinline__ unsigned short f2bf(float f) {
  unsigned int u = __float_as_uint(f);
  unsigned int r = (u + 0x7fffu + ((u >> 16) & 1u)) >> 16;
  return (unsigned short)r;
}

// async global->LDS, 16B per lane. LDS dest = wave-uniform base + lane*16.
// Global source IS per-lane -> swizzled LDS via pre-swizzled source (rule #21).
__device__ __forceinline__ void gload_lds16(const void* g, void* l) {
  __builtin_amdgcn_global_load_lds(
      (const __attribute__((address_space(1))) void*)(uintptr_t)g,
      (__attribute__((address_space(3))) void*)(uintptr_t)l, 16, 0, 0);
}

// fp32 -> bf16 conversion, 4 elems/thread. n must be a multiple of 4.
__global__ void conv_kernel(const float* __restrict__ src,
                            unsigned short* __restrict__ dst, long n) {
  long i = ((long)blockIdx.x * 256 + threadIdx.x) * 4;
  if (i < n) {
    float4 v = *(const float4*)(src + i);
    ushort4 o;
    o.x = f2bf(v.x); o.y = f2bf(v.y); o.z = f2bf(v.z); o.w = f2bf(v.w);
    *(ushort4*)(dst + i) = o;
  }
}

// ---------------------------------------------------------------------------
// GEMM helpers (Q is a template param so all acc indices are compile-time).
__device__ __forceinline__ void ds_read_B8(const short* Bb, int rB0, int l16,
                                           int quad, bf16x8 bfr[4][2]) {
  const int sw = l16 & 7;
#pragma unroll
  for (int ni = 0; ni < 4; ++ni)
#pragma unroll
    for (int ks = 0; ks < 2; ++ks)
      bfr[ni][ks] = *(const bf16x8*)
          &Bb[(rB0 + ni * 16 + l16) * 64 + (((ks * 4 + quad) ^ sw) * 8)];
}

template <int Q>
__device__ __forceinline__ void ds_read_A4(const short* Ab, int l16, int quad,
                                           bf16x8 af[2][2]) {
  const int sw = l16 & 7;
#pragma unroll
  for (int i = 0; i < 2; ++i)
#pragma unroll
    for (int ks = 0; ks < 2; ++ks)
      af[i][ks] = *(const bf16x8*)
          &Ab[((Q * 2 + i) * 16 + l16) * 64 + (((ks * 4 + quad) ^ sw) * 8)];
}

template <int Q>
__device__ __forceinline__ void mfma16(f32x4 acc[8][4], bf16x8 af[2][2],
                                       bf16x8 bfr[4][2]) {
#pragma unroll
  for (int i = 0; i < 2; ++i)
#pragma unroll
    for (int ni = 0; ni < 4; ++ni)
#pragma unroll
      for (int ks = 0; ks < 2; ++ks)
        acc[Q * 2 + i][ni] = __builtin_amdgcn_mfma_f32_16x16x32_bf16(
            af[i][ks], bfr[ni][ks], acc[Q * 2 + i][ni], 0, 0, 0);
}

// ---------------------------------------------------------------------------
// C[m][n] = sum_k A[m][k] * Bt[n][k] + bias[n]. A,Bt bf16; bias fp32.
// 256x256 tile, 512 thr = 8 waves (2M x 4N), BK=64, 4 phases/K-tile.
// Whole-buffer double-buffering; counted vmcnt steady 4/5/6/3 (never 0 in
// main loop); T2 swizzle via pre-swizzled global source; T5 setprio.
// M,N multiples of 256, K multiple of 64, K/64 >= 2.
template <bool OUT_F32>
__global__ __launch_bounds__(512, 2) void gemm_bt_kernel(
    const bf16* __restrict__ A, const bf16* __restrict__ Bt,
    const float* __restrict__ bias, void* __restrict__ Cout,
    int Ndim, int Kdim)
{
  __shared__ short lds[65536];  // A0 [0,16K) A1 [16K,32K) B0 [32K,48K) B1 [48K,64K) shorts
  const int tid = threadIdx.x;
  const int lane = tid & 63;
  const int w = tid >> 6;
  const int wr = w >> 2;        // 0..1  (M warps)
  const int wc = w & 3;         // 0..3  (N warps)
  const int quad = lane >> 4, l16 = lane & 15;

  // bijective XCD-aware block swizzle (m204)
  int gx = gridDim.x;
  int nwg = gx * gridDim.y;
  int flat = blockIdx.y * gx + blockIdx.x;
  int qq = nwg >> 3, rr = nwg & 7;
  int xcd = flat & 7, sub = flat >> 3;
  int wg = (xcd < rr ? xcd * (qq + 1) : rr * (qq + 1) + (xcd - rr) * qq) + sub;
  long m0 = (long)(wg / gx) * 256;
  long n0 = (long)(wg % gx) * 256;

  // staging geometry. Source colseg pre-swizzled: (lane&7) ^ ((lane>>3)&7).
  const int r8 = lane >> 3;
  const int csw = ((lane & 7) ^ (r8 & 7)) * 8;
  const bf16* gAs = A + (m0 + (w >> 2) * 128 + (w & 3) * 8 + r8) * (long)Kdim + csw;
  const bf16* gBs = Bt + (n0 + w * 8 + r8) * (long)Kdim + csw;
  short* dA = &lds[(w >> 2) * 8192 + (w & 3) * 512];   // + nd*16384 + qa*2048
  short* dB = &lds[32768 + w * 512];                   // + nd*16384 + j*4096
  const long kb64 = 64L * Kdim;   // B chunk row stride
  const long ka32 = 32L * Kdim;   // A quadrant row stride

  f32x4 acc[8][4];
#pragma unroll
  for (int i = 0; i < 8; i++)
#pragma unroll
    for (int j = 0; j < 4; j++)
      acc[i][j] = (f32x4){0.f, 0.f, 0.f, 0.f};

  const int NIT = Kdim >> 6;

  // prologue: stage tile 0 into buf 0 (order B0..B3, A0..A3)
#pragma unroll
  for (int j = 0; j < 4; ++j) gload_lds16(gBs + j * kb64, dB + j * 4096);
#pragma unroll
  for (int qa = 0; qa < 4; ++qa) gload_lds16(gAs + qa * ka32, dA + qa * 2048);
  asm volatile("s_waitcnt vmcnt(3)" ::: "memory");  // B*,A0 resident
  __builtin_amdgcn_s_barrier();

  bf16x8 bfr[4][2], af[2][2];

  for (int it = 0; it < NIT; ++it) {
    const int d = it & 1, nd = d ^ 1;
    const bool pf = (it < NIT - 1);
    const long kq1 = (long)(it + 1) * 64;
    const short* Ab = &lds[d * 16384 + wr * 8192];
    const short* Bb = &lds[32768 + d * 16384 + (wc >> 1) * 8192];
    const int rB0 = (wc & 1) * 64;
    short* dAn = dA + nd * 16384;
    short* dBn = dB + nd * 16384;

    // ---- phase 0: read all B + A q0; stage B0',B1' ----
    ds_read_B8(Bb, rB0, l16, quad, bfr);
    ds_read_A4<0>(Ab, l16, quad, af);
    if (pf) {
      gload_lds16(gBs + kq1, dBn);
      gload_lds16(gBs + kb64 + kq1, dBn + 4096);
      asm volatile("s_waitcnt vmcnt(4)" ::: "memory");   // A1 resident
    } else {
      asm volatile("s_waitcnt vmcnt(2)" ::: "memory");
    }
    asm volatile("s_waitcnt lgkmcnt(8)" ::: "memory");
    __builtin_amdgcn_s_barrier();
    asm volatile("s_waitcnt lgkmcnt(0)" ::: "memory");
    __builtin_amdgcn_sched_barrier(0);
    __builtin_amdgcn_s_setprio(1);
    mfma16<0>(acc, af, bfr);
    __builtin_amdgcn_s_setprio(0);
    __builtin_amdgcn_s_barrier();

    // ---- phase 1: read A q1; stage B2',B3' ----
    ds_read_A4<1>(Ab, l16, quad, af);
    if (pf) {
      gload_lds16(gBs + 2 * kb64 + kq1, dBn + 8192);
      gload_lds16(gBs + 3 * kb64 + kq1, dBn + 12288);
      asm volatile("s_waitcnt vmcnt(5)" ::: "memory");   // A2 resident
    } else {
      asm volatile("s_waitcnt vmcnt(1)" ::: "memory");
    }
    __builtin_amdgcn_s_barrier();
    asm volatile("s_waitcnt lgkmcnt(0)" ::: "memory");
    __builtin_amdgcn_sched_barrier(0);
    __builtin_amdgcn_s_setprio(1);
    mfma16<1>(acc, af, bfr);
    __builtin_amdgcn_s_setprio(0);
    __builtin_amdgcn_s_barrier();

    // ---- phase 2: read A q2; stage A0',A1' ----
    ds_read_A4<2>(Ab, l16, quad, af);
    if (pf) {
      gload_lds16(gAs + kq1, dAn);
      gload_lds16(gAs + ka32 + kq1, dAn + 2048);
      asm volatile("s_waitcnt vmcnt(6)" ::: "memory");   // A3 resident
    } else {
      asm volatile("s_waitcnt vmcnt(0)" ::: "memory");
    }
    __builtin_amdgcn_s_barrier();
    asm volatile("s_waitcnt lgkmcnt(0)" ::: "memory");
    __builtin_amdgcn_sched_barrier(0);
    __builtin_amdgcn_s_setprio(1);
    mfma16<2>(acc, af, bfr);
    __builtin_amdgcn_s_setprio(0);
    __builtin_amdgcn_s_barrier();

    // ---- phase 3: read A q3; stage A2',A3' ----
    ds_read_A4<3>(Ab, l16, quad, af);
    if (pf) {
      gload_lds16(gAs + 2 * ka32 + kq1, dAn + 4096);
      gload_lds16(gAs + 3 * ka32 + kq1, dAn + 6144);
      asm volatile("s_waitcnt vmcnt(3)" ::: "memory");   // B'*,A0' resident
    }
    __builtin_amdgcn_s_barrier();
    asm volatile("s_waitcnt lgkmcnt(0)" ::: "memory");
    __builtin_amdgcn_sched_barrier(0);
    __builtin_amdgcn_s_setprio(1);
    mfma16<3>(acc, af, bfr);
    __builtin_amdgcn_s_setprio(0);
    __builtin_amdgcn_s_barrier();
  }

  // epilogue
#pragma unroll
  for (int ni = 0; ni < 4; ++ni) {
    long col = n0 + wc * 64 + ni * 16 + l16;
    float bv = bias[col];
#pragma unroll
    for (int mi = 0; mi < 8; ++mi) {
      long row = m0 + wr * 128 + mi * 16 + quad * 4;
#pragma unroll
      for (int r = 0; r < 4; ++r) {
        float val = acc[mi][ni][r] + bv;
        if (OUT_F32)
          ((float*)Cout)[(row + r) * Ndim + col] = val;
        else
          ((bf16*)Cout)[(row + r) * Ndim + col] = __float2bfloat16(val);
      }
    }
  }
}

// ---------------------------------------------------------------------------
// kv_mfma v3: m-split, ZERO atomics.
// grid (96, 4): x = bh (keeps all 4 m-slice blocks of a bh on one XCD:
// flat%8 = bh%8), y = m-slice mb = 64*y. Block scans ALL 64 L-tiles,
// accumulates kv[64m][64d] + ksum[64m] in registers, plain-stores once.
// Per tile: MFMA1k: S[l][m] = sum_d k[l][d] pm[mb+m][d]; waves split l
//   (wave w = l-rows w*16..+15). kp3[m][l] = bf16(relu(S*ratio)+eps).
// MFMA2k: kv[m][d] += sum_l kp3[m][l] v[l][d]; waves split d
//   (wave w = d-slice w*16..+15).
// pm B-frags are loop-invariant (hoisted, 8 regs).
__global__ __launch_bounds__(256) void kv_mfma_kernel(
    const bf16* __restrict__ qkv, const bf16* __restrict__ pmb,
    float* __restrict__ kvbuf, float* __restrict__ ksumb)
{
  int bh = blockIdx.x;
  int b = bh / 12, h = bh % 12;
  int mb = blockIdx.y * 64;
  int tid = threadIdx.x, lane = tid & 63, w = tid >> 6;
  int quad = lane >> 4, l16 = lane & 15;

  __shared__ short k_lds[64 * 72];
  __shared__ short v_lds[64 * 72];   // stored swizzled: [l][d ^ (((l>>3)&3)<<4)]
  __shared__ short kp3[64 * 72];     // [m 0..63][l 0..63]
  __shared__ float red[4][64];

  // loop-invariant pm fragments for this block's m-slice
  bf16x8 bpm[4][2];
#pragma unroll
  for (int mt = 0; mt < 4; mt++)
#pragma unroll
    for (int ks = 0; ks < 2; ks++)
      bpm[mt][ks] = *(const bf16x8*)(pmb + (mb + mt * 16 + l16) * 64 + ks * 32 + quad * 8);

  f32x4 kvacc[4];   // [mt]; wave owns d-slice w*16..+15
#pragma unroll
  for (int mt = 0; mt < 4; mt++) kvacc[mt] = (f32x4){0.f, 0.f, 0.f, 0.f};
  float ksum_r = 0.f;

  int srow = tid >> 2, sseg = (tid & 3) * 8;
  int swz = ((srow >> 3) & 3) << 4;
  int mm = tid & 63, lq = tid >> 6;   // ksum ownership (bijective over 256)

  for (int tile = 0; tile < 64; tile++) {
    long gr = ((long)(b * 4096 + tile * 64 + srow)) * 2304 + h * 64;
    uint4 kk0 = *(const uint4*)(qkv + gr + 768 + sseg);
    uint4 kk1 = *(const uint4*)(qkv + gr + 768 + sseg + 32);
    uint4 vv0 = *(const uint4*)(qkv + gr + 1536 + sseg);
    uint4 vv1 = *(const uint4*)(qkv + gr + 1536 + sseg + 32);
    __syncthreads();   // protect LDS from previous iteration readers
    *(uint4*)&k_lds[srow * 72 + sseg] = kk0;
    *(uint4*)&k_lds[srow * 72 + sseg + 32] = kk1;
    *(uint4*)&v_lds[srow * 72 + (sseg ^ swz)] = vv0;
    *(uint4*)&v_lds[srow * 72 + ((sseg + 32) ^ swz)] = vv1;
    __syncthreads();

    // MFMA1k: wave w covers l-rows w*16..+15, all 64 m
    {
      bf16x8 af[2];
#pragma unroll
      for (int ks = 0; ks < 2; ks++)
        af[ks] = *(const bf16x8*)&k_lds[(w * 16 + l16) * 72 + ks * 32 + quad * 8];
#pragma unroll
      for (int mt = 0; mt < 4; mt++) {
        f32x4 s = (f32x4){0.f, 0.f, 0.f, 0.f};
        s = __builtin_amdgcn_mfma_f32_16x16x32_bf16(af[0], bpm[mt][0], s, 0, 0, 0);
        s = __builtin_amdgcn_mfma_f32_16x16x32_bf16(af[1], bpm[mt][1], s, 0, 0, 0);
        ushort4 pk;
        pk.x = f2bf(fmaxf(s[0] * RATIO, 0.f) + EPS_F);
        pk.y = f2bf(fmaxf(s[1] * RATIO, 0.f) + EPS_F);
        pk.z = f2bf(fmaxf(s[2] * RATIO, 0.f) + EPS_F);
        pk.w = f2bf(fmaxf(s[3] * RATIO, 0.f) + EPS_F);
        // rows l = w*16 + quad*4 + r, col m = mt*16 + l16
        *(ushort4*)&kp3[(mt * 16 + l16) * 72 + w * 16 + quad * 4] = pk;
      }
    }
    __syncthreads();

    // ksum: thread (mm, lq) sums 16 l of kp3 row mm
#pragma unroll
    for (int j = 0; j < 2; j++) {
      uint4 u = *(const uint4*)&kp3[mm * 72 + lq * 16 + j * 8];
      float f[8]; unpack8(u, f);
      ksum_r += ((f[0] + f[1]) + (f[2] + f[3])) + ((f[4] + f[5]) + (f[6] + f[7]));
    }

    // MFMA2k: wave w owns d-slice w*16..+15
#pragma unroll
    for (int ls = 0; ls < 2; ls++) {
      bf16x8 a2[4];
#pragma unroll
      for (int mt = 0; mt < 4; mt++)
        a2[mt] = *(const bf16x8*)&kp3[(mt * 16 + l16) * 72 + ls * 32 + quad * 8];
      bf16x8 b2;
      int dcol = (w * 16 + l16) ^ (quad << 4);
#pragma unroll
      for (int jj = 0; jj < 8; jj++)
        b2[jj] = v_lds[(ls * 32 + quad * 8 + jj) * 72 + dcol];
#pragma unroll
      for (int mt = 0; mt < 4; mt++)
        kvacc[mt] = __builtin_amdgcn_mfma_f32_16x16x32_bf16(a2[mt], b2, kvacc[mt], 0, 0, 0);
    }
  }

  // plain stores: C rows m = mt*16+quad*4+r (local), col d = w*16+l16
#pragma unroll
  for (int mt = 0; mt < 4; mt++)
#pragma unroll
    for (int r = 0; r < 4; r++)
      kvbuf[(long)bh * 16384 + (w * 16 + l16) * 256 + mb + mt * 16 + quad * 4 + r] =
          kvacc[mt][r];

  red[lq][mm] = ksum_r;
  __syncthreads();
  if (tid < 64)
    ksumb[bh * 256 + mb + tid] =
        (red[0][tid] + red[1][tid]) + (red[2][tid] + red[3][tid]);
}

// ---------------------------------------------------------------------------
// attn_mfma: per (b,h) x 64 L-rows.  (round-3 verified version)
// MFMA1: S[m][l] = sum_d pm[m][d] q[l][d]  (C: row=m, col=l)
// qp2[l][m] = bf16(relu(S*ratio)+eps)
// den[l] = sum_m qp2[l][m]*ksum[m]  (thread-parallel + LDS reduce)
// MFMA2: num[l][d] = sum_m qp2[l][m] * kvt[d][m]  (C: row=l, col=d)
__global__ __launch_bounds__(256) void attn_mfma_kernel(
    const bf16* __restrict__ qkv, const bf16* __restrict__ pmb,
    const bf16* __restrict__ kvtb, const float* __restrict__ ksumb,
    bf16* __restrict__ attn)
{
  int bh = blockIdx.x;
  int b = bh / 12, h = bh % 12;
  int l0 = blockIdx.y * 64;
  int tid = threadIdx.x, lane = tid & 63, w = tid >> 6;
  int quad = lane >> 4, l16 = lane & 15;

  __shared__ short q_lds[64 * 72];
  __shared__ short qp2[64 * 264];     // [l][m]
  __shared__ short kvt_lds[64 * 264]; // [d][m]
  __shared__ float ksum_lds[256];
  __shared__ float den_part[4][64];

  {
    int srow = tid >> 2, sseg = (tid & 3) * 8;
    long gr = ((long)(b * 4096 + l0 + srow)) * 2304 + h * 64;
    *(uint4*)&q_lds[srow * 72 + sseg]      = *(const uint4*)(qkv + gr + sseg);
    *(uint4*)&q_lds[srow * 72 + sseg + 32] = *(const uint4*)(qkv + gr + sseg + 32);
  }
  {
    int row = tid >> 2, cb = (tid & 3) * 64;
    const bf16* src = kvtb + (long)bh * 16384 + row * 256 + cb;
    short* dst = &kvt_lds[row * 264 + cb];
#pragma unroll
    for (int j = 0; j < 8; j++)
      *(uint4*)(dst + j * 8) = *(const uint4*)(src + j * 8);
  }
  ksum_lds[tid] = ksumb[bh * 256 + tid];
  __syncthreads();

  // MFMA1
  {
    bf16x8 apm[4][2], bq[4][2];
#pragma unroll
    for (int mt = 0; mt < 4; mt++)
#pragma unroll
      for (int ks = 0; ks < 2; ks++)
        apm[mt][ks] = *(const bf16x8*)(pmb + (w * 64 + mt * 16 + l16) * 64 + ks * 32 + quad * 8);
#pragma unroll
    for (int lt = 0; lt < 4; lt++)
#pragma unroll
      for (int ks = 0; ks < 2; ks++)
        bq[lt][ks] = *(const bf16x8*)&q_lds[(lt * 16 + l16) * 72 + ks * 32 + quad * 8];

#pragma unroll
    for (int mt = 0; mt < 4; mt++)
#pragma unroll
      for (int lt = 0; lt < 4; lt++) {
        f32x4 s = (f32x4){0.f, 0.f, 0.f, 0.f};
        s = __builtin_amdgcn_mfma_f32_16x16x32_bf16(apm[mt][0], bq[lt][0], s, 0, 0, 0);
        s = __builtin_amdgcn_mfma_f32_16x16x32_bf16(apm[mt][1], bq[lt][1], s, 0, 0, 0);
        ushort4 pk;
        pk.x = f2bf(fmaxf(s[0] * RATIO, 0.f) + EPS_F);
        pk.y = f2bf(fmaxf(s[1] * RATIO, 0.f) + EPS_F);
        pk.z = f2bf(fmaxf(s[2] * RATIO, 0.f) + EPS_F);
        pk.w = f2bf(fmaxf(s[3] * RATIO, 0.f) + EPS_F);
        // row l = lt*16 + l16, cols m = w*64 + mt*16 + quad*4 + r
        *(ushort4*)&qp2[(lt * 16 + l16) * 264 + w * 64 + mt * 16 + quad * 4] = pk;
      }
  }
  __syncthreads();

  // den partials
  {
    int l = tid & 63, Q = tid >> 6;
    float dp = 0.f;
#pragma unroll
    for (int j8 = 0; j8 < 8; j8++) {
      uint4 u = *(const uint4*)&qp2[l * 264 + Q * 64 + j8 * 8];
      float f[8]; unpack8(u, f);
#pragma unroll
      for (int i = 0; i < 8; i++) dp += f[i] * ksum_lds[Q * 64 + j8 * 8 + i];
    }
    den_part[Q][l] = dp;
  }

  // MFMA2: wave strip l = w*16..w*16+15
  f32x4 o[4];
#pragma unroll
  for (int dt = 0; dt < 4; dt++) o[dt] = (f32x4){0.f, 0.f, 0.f, 0.f};
#pragma unroll
  for (int ms = 0; ms < 8; ms++) {
    bf16x8 aq = *(const bf16x8*)&qp2[(w * 16 + l16) * 264 + ms * 32 + quad * 8];
#pragma unroll
    for (int dt = 0; dt < 4; dt++) {
      bf16x8 bk = *(const bf16x8*)&kvt_lds[(dt * 16 + l16) * 264 + ms * 32 + quad * 8];
      o[dt] = __builtin_amdgcn_mfma_f32_16x16x32_bf16(aq, bk, o[dt], 0, 0, 0);
    }
  }
  __syncthreads();

  float rden[4];
#pragma unroll
  for (int r = 0; r < 4; r++) {
    int l = w * 16 + quad * 4 + r;
    rden[r] = 1.f / (den_part[0][l] + den_part[1][l] + den_part[2][l] + den_part[3][l]);
  }
#pragma unroll
  for (int dt = 0; dt < 4; dt++)
#pragma unroll
    for (int r = 0; r < 4; r++) {
      int l = w * 16 + quad * 4 + r;
      attn[((long)(b * 4096 + l0 + l)) * 768 + h * 64 + dt * 16 + l16] =
          __float2bfloat16(o[dt][r] * rden[r]);
    }
}

extern "C" void kernel_launch(void* const* d_in, const int* in_sizes, int n_in,
                              void* d_out, int out_size, void* d_ws, size_t ws_size,
                              hipStream_t stream)
{
  const float* x      = (const float*)d_in[0];
  const float* qkv_w  = (const float*)d_in[1];
  const float* qkv_b  = (const float*)d_in[2];
  const float* proj_w = (const float*)d_in[3];
  const float* proj_b = (const float*)d_in[4];
  const float* pmat   = (const float*)d_in[5];
  float* out = (float*)d_out;

  // ws layout (212,434,944 B total):
  //   qkv   bf16  [0, 150994944)
  //   xbuf  bf16  [150994944, 201326592)   (attn aliases; disjoint lifetime)
  //   kvbuf fp32  [201326592, 207618048)   96*64*256  (plain stores, no zero)
  //   ksumb fp32  [207618048, 207716352)   96*256     (plain stores, no zero)
  //   wqkv  bf16  [207716352, 211255296)   dead after gemm1; kvtb+pmb alias in
  //     kvtb bf16 [207716352, 210862080)   96*64*256
  //     pmb  bf16 [210862080, 210894848)   256*64
  //   wproj bf16  [211255296, 212434944)
  char* ws = (char*)d_ws;
  bf16*  qkv   = (bf16*)ws;
  bf16*  xbuf  = (bf16*)(ws + 150994944);
  bf16*  attn  = xbuf;
  float* kvbuf = (float*)(ws + 201326592);
  float* ksumb = (float*)(ws + 207618048);
  bf16*  wqkv  = (bf16*)(ws + 207716352);
  bf16*  kvtb  = (bf16*)(ws + 207716352);
  bf16*  pmb   = (bf16*)(ws + 210862080);
  bf16*  wproj = (bf16*)(ws + 211255296);

  conv_kernel<<<dim3(25165824 / 1024), 256, 0, stream>>>(x, (unsigned short*)xbuf, 25165824L);
  conv_kernel<<<dim3(1769472 / 1024), 256, 0, stream>>>(qkv_w, (unsigned short*)wqkv, 1769472L);
  conv_kernel<<<dim3(589824 / 1024), 256, 0, stream>>>(proj_w, (unsigned short*)wproj, 589824L);

  // QKV projection: (32768 x 768) @ (2304 x 768)^T -> bf16 qkv
  gemm_bt_kernel<false><<<dim3(2304 / 256, 32768 / 256), 512, 0, stream>>>(
      xbuf, wqkv, qkv_b, qkv, 2304, 768);

  // pm -> bf16 (region overlaps wqkv tail: must be after gemm1)
  conv_kernel<<<dim3(16384 / 1024), 256, 0, stream>>>(pmat, (unsigned short*)pmb, 16384L);

  // kv + ksum (MFMA, m-split, no atomics)
  kv_mfma_kernel<<<dim3(96, 4), 256, 0, stream>>>(qkv, pmb, kvbuf, ksumb);

  // kvbuf fp32 -> kvtb bf16 (overlaps wqkv front: after gemm1; after kv_mfma)
  conv_kernel<<<dim3(1572864 / 1024), 256, 0, stream>>>(kvbuf, (unsigned short*)kvtb, 1572864L);

  // q features + num/den + normalize -> bf16 attn (MFMA)
  attn_mfma_kernel<<<dim3(96, 64), 256, 0, stream>>>(qkv, pmb, kvtb, ksumb, attn);

  // output projection: (32768 x 768) @ (768 x 768)^T -> fp32 out
  gemm_bt_kernel<true><<<dim3(768 / 256, 32768 / 256), 512, 0, stream>>>(
      attn, wproj, proj_b, out, 768, 768);
}

// Round 6
// 541.600 us; speedup vs baseline: 1.3085x; 1.0358x over previous
//
#include <hip/hip_runtime.h>
#include <hip/hip_bf16.h>
#include <cstdint>

typedef __hip_bfloat16 bf16;
typedef short bf16x8 __attribute__((ext_vector_type(8)));
typedef float f32x4 __attribute__((ext_vector_type(4)));

#define RATIO 0.0625f
#define EPS_F 0.001f

__device__ __forceinline__ void unpack8(uint4 u, float* f) {
  f[0] = __uint_as_float(u.x << 16); f[1] = __uint_as_float(u.x & 0xffff0000u);
  f[2] = __uint_as_float(u.y << 16); f[3] = __uint_as_float(u.y & 0xffff0000u);
  f[4] = __uint_as_float(u.z << 16); f[5] = __uint_as_float(u.z & 0xffff0000u);
  f[6] = __uint_as_float(u.w << 16); f[7] = __uint_as_float(u.w & 0xffff0000u);
}

__device__ __forceinline__ unsigned short f2bf(float f) {
  unsigned int u = __float_as_uint(f);
  unsigned int r = (u + 0x7fffu + ((u >> 16) & 1u)) >> 16;
  return (unsigned short)r;
}

// async global->LDS, 16B per lane. LDS dest = wave-uniform base + lane*16.
// Global source IS per-lane -> swizzled LDS via pre-swizzled source (rule #21).
__device__ __forceinline__ void gload_lds16(const void* g, void* l) {
  __builtin_amdgcn_global_load_lds(
      (const __attribute__((address_space(1))) void*)(uintptr_t)g,
      (__attribute__((address_space(3))) void*)(uintptr_t)l, 16, 0, 0);
}

// fp32 -> bf16 conversion, 4 elems/thread. n must be a multiple of 4.
__global__ void conv_kernel(const float* __restrict__ src,
                            unsigned short* __restrict__ dst, long n) {
  long i = ((long)blockIdx.x * 256 + threadIdx.x) * 4;
  if (i < n) {
    float4 v = *(const float4*)(src + i);
    ushort4 o;
    o.x = f2bf(v.x); o.y = f2bf(v.y); o.z = f2bf(v.z); o.w = f2bf(v.w);
    *(ushort4*)(dst + i) = o;
  }
}

// add two fp32 partial kv buffers -> bf16 kvtb; add ksum partials in-place.
__global__ void kv_add_kernel(const float* __restrict__ a,
                              const float* __restrict__ b,
                              unsigned short* __restrict__ kvtb,
                              float* __restrict__ ks_a,
                              const float* __restrict__ ks_b) {
  long i4 = ((long)blockIdx.x * 256 + threadIdx.x) * 4;
  if (i4 < 1572864) {
    float4 x = *(const float4*)(a + i4);
    float4 y = *(const float4*)(b + i4);
    ushort4 o;
    o.x = f2bf(x.x + y.x); o.y = f2bf(x.y + y.y);
    o.z = f2bf(x.z + y.z); o.w = f2bf(x.w + y.w);
    *(ushort4*)(kvtb + i4) = o;
  }
  if (i4 < 24576) {
    float4 p = *(const float4*)(ks_a + i4);
    float4 q = *(const float4*)(ks_b + i4);
    p.x += q.x; p.y += q.y; p.z += q.z; p.w += q.w;
    *(float4*)(ks_a + i4) = p;
  }
}

// ---------------------------------------------------------------------------
// GEMM helpers (Q is a template param so all acc indices are compile-time).
__device__ __forceinline__ void ds_read_B8(const short* Bb, int rB0, int l16,
                                           int quad, bf16x8 bfr[4][2]) {
  const int sw = l16 & 7;
#pragma unroll
  for (int ni = 0; ni < 4; ++ni)
#pragma unroll
    for (int ks = 0; ks < 2; ++ks)
      bfr[ni][ks] = *(const bf16x8*)
          &Bb[(rB0 + ni * 16 + l16) * 64 + (((ks * 4 + quad) ^ sw) * 8)];
}

template <int Q>
__device__ __forceinline__ void ds_read_A4(const short* Ab, int l16, int quad,
                                           bf16x8 af[2][2]) {
  const int sw = l16 & 7;
#pragma unroll
  for (int i = 0; i < 2; ++i)
#pragma unroll
    for (int ks = 0; ks < 2; ++ks)
      af[i][ks] = *(const bf16x8*)
          &Ab[((Q * 2 + i) * 16 + l16) * 64 + (((ks * 4 + quad) ^ sw) * 8)];
}

template <int Q>
__device__ __forceinline__ void mfma16(f32x4 acc[8][4], bf16x8 af[2][2],
                                       bf16x8 bfr[4][2]) {
#pragma unroll
  for (int i = 0; i < 2; ++i)
#pragma unroll
    for (int ni = 0; ni < 4; ++ni)
#pragma unroll
      for (int ks = 0; ks < 2; ++ks)
        acc[Q * 2 + i][ni] = __builtin_amdgcn_mfma_f32_16x16x32_bf16(
            af[i][ks], bfr[ni][ks], acc[Q * 2 + i][ni], 0, 0, 0);
}

// ---------------------------------------------------------------------------
// C[m][n] = sum_k A[m][k] * Bt[n][k] + bias[n]. A,Bt bf16; bias fp32.
// 256x256 tile, 512 thr = 8 waves (2M x 4N), BK=64, 4 phases/K-tile.
// Whole-buffer double-buffering; counted vmcnt steady 4/5/6/3 (never 0 in
// main loop); T2 swizzle via pre-swizzled global source; T5 setprio.
// M,N multiples of 256, K multiple of 64, K/64 >= 2.
template <bool OUT_F32>
__global__ __launch_bounds__(512, 2) void gemm_bt_kernel(
    const bf16* __restrict__ A, const bf16* __restrict__ Bt,
    const float* __restrict__ bias, void* __restrict__ Cout,
    int Ndim, int Kdim)
{
  __shared__ short lds[65536];  // A0 [0,16K) A1 [16K,32K) B0 [32K,48K) B1 [48K,64K) shorts
  const int tid = threadIdx.x;
  const int lane = tid & 63;
  const int w = tid >> 6;
  const int wr = w >> 2;        // 0..1  (M warps)
  const int wc = w & 3;         // 0..3  (N warps)
  const int quad = lane >> 4, l16 = lane & 15;

  // bijective XCD-aware block swizzle (m204)
  int gx = gridDim.x;
  int nwg = gx * gridDim.y;
  int flat = blockIdx.y * gx + blockIdx.x;
  int qq = nwg >> 3, rr = nwg & 7;
  int xcd = flat & 7, sub = flat >> 3;
  int wg = (xcd < rr ? xcd * (qq + 1) : rr * (qq + 1) + (xcd - rr) * qq) + sub;
  long m0 = (long)(wg / gx) * 256;
  long n0 = (long)(wg % gx) * 256;

  // staging geometry. Source colseg pre-swizzled: (lane&7) ^ ((lane>>3)&7).
  const int r8 = lane >> 3;
  const int csw = ((lane & 7) ^ (r8 & 7)) * 8;
  const bf16* gAs = A + (m0 + (w >> 2) * 128 + (w & 3) * 8 + r8) * (long)Kdim + csw;
  const bf16* gBs = Bt + (n0 + w * 8 + r8) * (long)Kdim + csw;
  short* dA = &lds[(w >> 2) * 8192 + (w & 3) * 512];   // + nd*16384 + qa*2048
  short* dB = &lds[32768 + w * 512];                   // + nd*16384 + j*4096
  const long kb64 = 64L * Kdim;   // B chunk row stride
  const long ka32 = 32L * Kdim;   // A quadrant row stride

  f32x4 acc[8][4];
#pragma unroll
  for (int i = 0; i < 8; i++)
#pragma unroll
    for (int j = 0; j < 4; j++)
      acc[i][j] = (f32x4){0.f, 0.f, 0.f, 0.f};

  const int NIT = Kdim >> 6;

  // prologue: stage tile 0 into buf 0 (order B0..B3, A0..A3)
#pragma unroll
  for (int j = 0; j < 4; ++j) gload_lds16(gBs + j * kb64, dB + j * 4096);
#pragma unroll
  for (int qa = 0; qa < 4; ++qa) gload_lds16(gAs + qa * ka32, dA + qa * 2048);
  asm volatile("s_waitcnt vmcnt(3)" ::: "memory");  // B*,A0 resident
  __builtin_amdgcn_s_barrier();

  bf16x8 bfr[4][2], af[2][2];

  for (int it = 0; it < NIT; ++it) {
    const int d = it & 1, nd = d ^ 1;
    const bool pf = (it < NIT - 1);
    const long kq1 = (long)(it + 1) * 64;
    const short* Ab = &lds[d * 16384 + wr * 8192];
    const short* Bb = &lds[32768 + d * 16384 + (wc >> 1) * 8192];
    const int rB0 = (wc & 1) * 64;
    short* dAn = dA + nd * 16384;
    short* dBn = dB + nd * 16384;

    // ---- phase 0: read all B + A q0; stage B0',B1' ----
    ds_read_B8(Bb, rB0, l16, quad, bfr);
    ds_read_A4<0>(Ab, l16, quad, af);
    if (pf) {
      gload_lds16(gBs + kq1, dBn);
      gload_lds16(gBs + kb64 + kq1, dBn + 4096);
      asm volatile("s_waitcnt vmcnt(4)" ::: "memory");   // A1 resident
    } else {
      asm volatile("s_waitcnt vmcnt(2)" ::: "memory");
    }
    asm volatile("s_waitcnt lgkmcnt(8)" ::: "memory");
    __builtin_amdgcn_s_barrier();
    asm volatile("s_waitcnt lgkmcnt(0)" ::: "memory");
    __builtin_amdgcn_sched_barrier(0);
    __builtin_amdgcn_s_setprio(1);
    mfma16<0>(acc, af, bfr);
    __builtin_amdgcn_s_setprio(0);
    __builtin_amdgcn_s_barrier();

    // ---- phase 1: read A q1; stage B2',B3' ----
    ds_read_A4<1>(Ab, l16, quad, af);
    if (pf) {
      gload_lds16(gBs + 2 * kb64 + kq1, dBn + 8192);
      gload_lds16(gBs + 3 * kb64 + kq1, dBn + 12288);
      asm volatile("s_waitcnt vmcnt(5)" ::: "memory");   // A2 resident
    } else {
      asm volatile("s_waitcnt vmcnt(1)" ::: "memory");
    }
    __builtin_amdgcn_s_barrier();
    asm volatile("s_waitcnt lgkmcnt(0)" ::: "memory");
    __builtin_amdgcn_sched_barrier(0);
    __builtin_amdgcn_s_setprio(1);
    mfma16<1>(acc, af, bfr);
    __builtin_amdgcn_s_setprio(0);
    __builtin_amdgcn_s_barrier();

    // ---- phase 2: read A q2; stage A0',A1' ----
    ds_read_A4<2>(Ab, l16, quad, af);
    if (pf) {
      gload_lds16(gAs + kq1, dAn);
      gload_lds16(gAs + ka32 + kq1, dAn + 2048);
      asm volatile("s_waitcnt vmcnt(6)" ::: "memory");   // A3 resident
    } else {
      asm volatile("s_waitcnt vmcnt(0)" ::: "memory");
    }
    __builtin_amdgcn_s_barrier();
    asm volatile("s_waitcnt lgkmcnt(0)" ::: "memory");
    __builtin_amdgcn_sched_barrier(0);
    __builtin_amdgcn_s_setprio(1);
    mfma16<2>(acc, af, bfr);
    __builtin_amdgcn_s_setprio(0);
    __builtin_amdgcn_s_barrier();

    // ---- phase 3: read A q3; stage A2',A3' ----
    ds_read_A4<3>(Ab, l16, quad, af);
    if (pf) {
      gload_lds16(gAs + 2 * ka32 + kq1, dAn + 4096);
      gload_lds16(gAs + 3 * ka32 + kq1, dAn + 6144);
      asm volatile("s_waitcnt vmcnt(3)" ::: "memory");   // B'*,A0' resident
    }
    __builtin_amdgcn_s_barrier();
    asm volatile("s_waitcnt lgkmcnt(0)" ::: "memory");
    __builtin_amdgcn_sched_barrier(0);
    __builtin_amdgcn_s_setprio(1);
    mfma16<3>(acc, af, bfr);
    __builtin_amdgcn_s_setprio(0);
    __builtin_amdgcn_s_barrier();
  }

  // epilogue
#pragma unroll
  for (int ni = 0; ni < 4; ++ni) {
    long col = n0 + wc * 64 + ni * 16 + l16;
    float bv = bias[col];
#pragma unroll
    for (int mi = 0; mi < 8; ++mi) {
      long row = m0 + wr * 128 + mi * 16 + quad * 4;
#pragma unroll
      for (int r = 0; r < 4; ++r) {
        float val = acc[mi][ni][r] + bv;
        if (OUT_F32)
          ((float*)Cout)[(row + r) * Ndim + col] = val;
        else
          ((bf16*)Cout)[(row + r) * Ndim + col] = __float2bfloat16(val);
      }
    }
  }
}

// ---------------------------------------------------------------------------
// kv_mfma v4: m-split + L-split, ZERO atomics, reg-prefetch (T14).
// grid (96, 4, 2): x = bh (XCD locality), y = m-slice mb = 64*y,
// z = L-half (rows z*2048 .. +2047, 32 tiles of 64).
// Block accumulates kv[64m][64d] + ksum[64m] in registers over its 32 tiles,
// plain-stores into the z-selected fp32 partial buffer; kv_add_kernel sums
// the two halves and converts to bf16 kvtb.
// Per tile: MFMA1k: S[l][m] = sum_d k[l][d] pm[mb+m][d]; waves split l.
// kp3[m][l] = bf16(relu(S*ratio)+eps). MFMA2k: kv[m][d] += kp3[m][l] v[l][d];
// waves split d. pm B-frags loop-invariant (8 regs). Tile t+1's global loads
// are issued right after MFMA1k consumes the regs -> latency hides under
// kp3-barrier + ksum + MFMA2k.
__global__ __launch_bounds__(256) void kv_mfma_kernel(
    const bf16* __restrict__ qkv, const bf16* __restrict__ pmb,
    float* __restrict__ kvp0, float* __restrict__ kvp1,
    float* __restrict__ ksp0, float* __restrict__ ksp1)
{
  int bh = blockIdx.x;
  int b = bh / 12, h = bh % 12;
  int mb = blockIdx.y * 64;
  int zh = blockIdx.z;
  float* kvout = zh ? kvp1 : kvp0;
  float* ksout = zh ? ksp1 : ksp0;
  int l0 = zh * 2048;
  int tid = threadIdx.x, lane = tid & 63, w = tid >> 6;
  int quad = lane >> 4, l16 = lane & 15;

  __shared__ short k_lds[64 * 72];
  __shared__ short v_lds[64 * 72];   // stored swizzled: [l][d ^ (((l>>3)&3)<<4)]
  __shared__ short kp3[64 * 72];     // [m 0..63][l 0..63]
  __shared__ float red[4][64];

  // loop-invariant pm fragments for this block's m-slice
  bf16x8 bpm[4][2];
#pragma unroll
  for (int mt = 0; mt < 4; mt++)
#pragma unroll
    for (int ks = 0; ks < 2; ks++)
      bpm[mt][ks] = *(const bf16x8*)(pmb + (mb + mt * 16 + l16) * 64 + ks * 32 + quad * 8);

  f32x4 kvacc[4];   // [mt]; wave owns d-slice w*16..+15
#pragma unroll
  for (int mt = 0; mt < 4; mt++) kvacc[mt] = (f32x4){0.f, 0.f, 0.f, 0.f};
  float ksum_r = 0.f;

  int srow = tid >> 2, sseg = (tid & 3) * 8;
  int swz = ((srow >> 3) & 3) << 4;
  int mm = tid & 63, lq = tid >> 6;   // ksum ownership (bijective over 256)

  // prologue: tile 0 into regs
  long gr = ((long)(b * 4096 + l0 + srow)) * 2304 + h * 64;
  uint4 kk0 = *(const uint4*)(qkv + gr + 768 + sseg);
  uint4 kk1 = *(const uint4*)(qkv + gr + 768 + sseg + 32);
  uint4 vv0 = *(const uint4*)(qkv + gr + 1536 + sseg);
  uint4 vv1 = *(const uint4*)(qkv + gr + 1536 + sseg + 32);

  for (int tile = 0; tile < 32; tile++) {
    __syncthreads();   // previous iteration's kp3/v_lds readers done
    *(uint4*)&k_lds[srow * 72 + sseg] = kk0;
    *(uint4*)&k_lds[srow * 72 + sseg + 32] = kk1;
    *(uint4*)&v_lds[srow * 72 + (sseg ^ swz)] = vv0;
    *(uint4*)&v_lds[srow * 72 + ((sseg + 32) ^ swz)] = vv1;
    __syncthreads();

    // MFMA1k: wave w covers l-rows w*16..+15, all 64 m
    {
      bf16x8 af[2];
#pragma unroll
      for (int ks = 0; ks < 2; ks++)
        af[ks] = *(const bf16x8*)&k_lds[(w * 16 + l16) * 72 + ks * 32 + quad * 8];
#pragma unroll
      for (int mt = 0; mt < 4; mt++) {
        f32x4 s = (f32x4){0.f, 0.f, 0.f, 0.f};
        s = __builtin_amdgcn_mfma_f32_16x16x32_bf16(af[0], bpm[mt][0], s, 0, 0, 0);
        s = __builtin_amdgcn_mfma_f32_16x16x32_bf16(af[1], bpm[mt][1], s, 0, 0, 0);
        ushort4 pk;
        pk.x = f2bf(fmaxf(s[0] * RATIO, 0.f) + EPS_F);
        pk.y = f2bf(fmaxf(s[1] * RATIO, 0.f) + EPS_F);
        pk.z = f2bf(fmaxf(s[2] * RATIO, 0.f) + EPS_F);
        pk.w = f2bf(fmaxf(s[3] * RATIO, 0.f) + EPS_F);
        // rows l = w*16 + quad*4 + r, col m = mt*16 + l16
        *(ushort4*)&kp3[(mt * 16 + l16) * 72 + w * 16 + quad * 4] = pk;
      }
    }

    // prefetch tile+1 into regs (latency hides under barrier + ksum + MFMA2k)
    if (tile < 31) {
      long g2 = ((long)(b * 4096 + l0 + (tile + 1) * 64 + srow)) * 2304 + h * 64;
      kk0 = *(const uint4*)(qkv + g2 + 768 + sseg);
      kk1 = *(const uint4*)(qkv + g2 + 768 + sseg + 32);
      vv0 = *(const uint4*)(qkv + g2 + 1536 + sseg);
      vv1 = *(const uint4*)(qkv + g2 + 1536 + sseg + 32);
    }
    __syncthreads();   // kp3 visible

    // ksum: thread (mm, lq) sums 16 l of kp3 row mm
#pragma unroll
    for (int j = 0; j < 2; j++) {
      uint4 u = *(const uint4*)&kp3[mm * 72 + lq * 16 + j * 8];
      float f[8]; unpack8(u, f);
      ksum_r += ((f[0] + f[1]) + (f[2] + f[3])) + ((f[4] + f[5]) + (f[6] + f[7]));
    }

    // MFMA2k: wave w owns d-slice w*16..+15
#pragma unroll
    for (int ls = 0; ls < 2; ls++) {
      bf16x8 a2[4];
#pragma unroll
      for (int mt = 0; mt < 4; mt++)
        a2[mt] = *(const bf16x8*)&kp3[(mt * 16 + l16) * 72 + ls * 32 + quad * 8];
      bf16x8 b2;
      int dcol = (w * 16 + l16) ^ (quad << 4);
#pragma unroll
      for (int jj = 0; jj < 8; jj++)
        b2[jj] = v_lds[(ls * 32 + quad * 8 + jj) * 72 + dcol];
#pragma unroll
      for (int mt = 0; mt < 4; mt++)
        kvacc[mt] = __builtin_amdgcn_mfma_f32_16x16x32_bf16(a2[mt], b2, kvacc[mt], 0, 0, 0);
    }
  }

  // plain stores: C rows m = mt*16+quad*4+r (local), col d = w*16+l16
#pragma unroll
  for (int mt = 0; mt < 4; mt++)
#pragma unroll
    for (int r = 0; r < 4; r++)
      kvout[(long)bh * 16384 + (w * 16 + l16) * 256 + mb + mt * 16 + quad * 4 + r] =
          kvacc[mt][r];

  red[lq][mm] = ksum_r;
  __syncthreads();
  if (tid < 64)
    ksout[bh * 256 + mb + tid] =
        (red[0][tid] + red[1][tid]) + (red[2][tid] + red[3][tid]);
}

// ---------------------------------------------------------------------------
// attn_mfma: per (b,h) x 64 L-rows.  (round-3/5 verified version)
// MFMA1: S[m][l] = sum_d pm[m][d] q[l][d]  (C: row=m, col=l)
// qp2[l][m] = bf16(relu(S*ratio)+eps)
// den[l] = sum_m qp2[l][m]*ksum[m]  (thread-parallel + LDS reduce)
// MFMA2: num[l][d] = sum_m qp2[l][m] * kvt[d][m]  (C: row=l, col=d)
__global__ __launch_bounds__(256) void attn_mfma_kernel(
    const bf16* __restrict__ qkv, const bf16* __restrict__ pmb,
    const bf16* __restrict__ kvtb, const float* __restrict__ ksumb,
    bf16* __restrict__ attn)
{
  int bh = blockIdx.x;
  int b = bh / 12, h = bh % 12;
  int l0 = blockIdx.y * 64;
  int tid = threadIdx.x, lane = tid & 63, w = tid >> 6;
  int quad = lane >> 4, l16 = lane & 15;

  __shared__ short q_lds[64 * 72];
  __shared__ short qp2[64 * 264];     // [l][m]
  __shared__ short kvt_lds[64 * 264]; // [d][m]
  __shared__ float ksum_lds[256];
  __shared__ float den_part[4][64];

  {
    int srow = tid >> 2, sseg = (tid & 3) * 8;
    long gr = ((long)(b * 4096 + l0 + srow)) * 2304 + h * 64;
    *(uint4*)&q_lds[srow * 72 + sseg]      = *(const uint4*)(qkv + gr + sseg);
    *(uint4*)&q_lds[srow * 72 + sseg + 32] = *(const uint4*)(qkv + gr + sseg + 32);
  }
  {
    int row = tid >> 2, cb = (tid & 3) * 64;
    const bf16* src = kvtb + (long)bh * 16384 + row * 256 + cb;
    short* dst = &kvt_lds[row * 264 + cb];
#pragma unroll
    for (int j = 0; j < 8; j++)
      *(uint4*)(dst + j * 8) = *(const uint4*)(src + j * 8);
  }
  ksum_lds[tid] = ksumb[bh * 256 + tid];
  __syncthreads();

  // MFMA1
  {
    bf16x8 apm[4][2], bq[4][2];
#pragma unroll
    for (int mt = 0; mt < 4; mt++)
#pragma unroll
      for (int ks = 0; ks < 2; ks++)
        apm[mt][ks] = *(const bf16x8*)(pmb + (w * 64 + mt * 16 + l16) * 64 + ks * 32 + quad * 8);
#pragma unroll
    for (int lt = 0; lt < 4; lt++)
#pragma unroll
      for (int ks = 0; ks < 2; ks++)
        bq[lt][ks] = *(const bf16x8*)&q_lds[(lt * 16 + l16) * 72 + ks * 32 + quad * 8];

#pragma unroll
    for (int mt = 0; mt < 4; mt++)
#pragma unroll
      for (int lt = 0; lt < 4; lt++) {
        f32x4 s = (f32x4){0.f, 0.f, 0.f, 0.f};
        s = __builtin_amdgcn_mfma_f32_16x16x32_bf16(apm[mt][0], bq[lt][0], s, 0, 0, 0);
        s = __builtin_amdgcn_mfma_f32_16x16x32_bf16(apm[mt][1], bq[lt][1], s, 0, 0, 0);
        ushort4 pk;
        pk.x = f2bf(fmaxf(s[0] * RATIO, 0.f) + EPS_F);
        pk.y = f2bf(fmaxf(s[1] * RATIO, 0.f) + EPS_F);
        pk.z = f2bf(fmaxf(s[2] * RATIO, 0.f) + EPS_F);
        pk.w = f2bf(fmaxf(s[3] * RATIO, 0.f) + EPS_F);
        // row l = lt*16 + l16, cols m = w*64 + mt*16 + quad*4 + r
        *(ushort4*)&qp2[(lt * 16 + l16) * 264 + w * 64 + mt * 16 + quad * 4] = pk;
      }
  }
  __syncthreads();

  // den partials
  {
    int l = tid & 63, Q = tid >> 6;
    float dp = 0.f;
#pragma unroll
    for (int j8 = 0; j8 < 8; j8++) {
      uint4 u = *(const uint4*)&qp2[l * 264 + Q * 64 + j8 * 8];
      float f[8]; unpack8(u, f);
#pragma unroll
      for (int i = 0; i < 8; i++) dp += f[i] * ksum_lds[Q * 64 + j8 * 8 + i];
    }
    den_part[Q][l] = dp;
  }

  // MFMA2: wave strip l = w*16..w*16+15
  f32x4 o[4];
#pragma unroll
  for (int dt = 0; dt < 4; dt++) o[dt] = (f32x4){0.f, 0.f, 0.f, 0.f};
#pragma unroll
  for (int ms = 0; ms < 8; ms++) {
    bf16x8 aq = *(const bf16x8*)&qp2[(w * 16 + l16) * 264 + ms * 32 + quad * 8];
#pragma unroll
    for (int dt = 0; dt < 4; dt++) {
      bf16x8 bk = *(const bf16x8*)&kvt_lds[(dt * 16 + l16) * 264 + ms * 32 + quad * 8];
      o[dt] = __builtin_amdgcn_mfma_f32_16x16x32_bf16(aq, bk, o[dt], 0, 0, 0);
    }
  }
  __syncthreads();

  float rden[4];
#pragma unroll
  for (int r = 0; r < 4; r++) {
    int l = w * 16 + quad * 4 + r;
    rden[r] = 1.f / (den_part[0][l] + den_part[1][l] + den_part[2][l] + den_part[3][l]);
  }
#pragma unroll
  for (int dt = 0; dt < 4; dt++)
#pragma unroll
    for (int r = 0; r < 4; r++) {
      int l = w * 16 + quad * 4 + r;
      attn[((long)(b * 4096 + l0 + l)) * 768 + h * 64 + dt * 16 + l16] =
          __float2bfloat16(o[dt][r] * rden[r]);
    }
}

extern "C" void kernel_launch(void* const* d_in, const int* in_sizes, int n_in,
                              void* d_out, int out_size, void* d_ws, size_t ws_size,
                              hipStream_t stream)
{
  const float* x      = (const float*)d_in[0];
  const float* qkv_w  = (const float*)d_in[1];
  const float* qkv_b  = (const float*)d_in[2];
  const float* proj_w = (const float*)d_in[3];
  const float* proj_b = (const float*)d_in[4];
  const float* pmat   = (const float*)d_in[5];
  float* out = (float*)d_out;

  // ws layout (212,434,944 B total):
  //   qkv   bf16  [0, 150994944)
  //   xbuf  bf16  [150994944, 201326592)   x-bf16 until gemm1;
  //     then kvp1 fp32 [150994944, 157286400) + ksp1 fp32 [157286400, 157384704)
  //     (dead before attn_mfma writes attn over this window)
  //   attn  bf16  [150994944, 201326592)   written by attn_mfma
  //   kvp0  fp32  [201326592, 207618048)   96*64*256 (plain stores)
  //   ksp0  fp32  [207618048, 207716352)   96*256; kv_add sums ksp1 in-place
  //   wqkv  bf16  [207716352, 211255296)   dead after gemm1; kvtb+pmb alias in
  //     kvtb bf16 [207716352, 210862080)   96*64*256
  //     pmb  bf16 [210862080, 210894848)   256*64
  //   wproj bf16  [211255296, 212434944)
  char* ws = (char*)d_ws;
  bf16*  qkv   = (bf16*)ws;
  bf16*  xbuf  = (bf16*)(ws + 150994944);
  bf16*  attn  = xbuf;
  float* kvp1  = (float*)(ws + 150994944);
  float* ksp1  = (float*)(ws + 157286400);
  float* kvp0  = (float*)(ws + 201326592);
  float* ksp0  = (float*)(ws + 207618048);
  float* ksumb = ksp0;
  bf16*  wqkv  = (bf16*)(ws + 207716352);
  bf16*  kvtb  = (bf16*)(ws + 207716352);
  bf16*  pmb   = (bf16*)(ws + 210862080);
  bf16*  wproj = (bf16*)(ws + 211255296);

  conv_kernel<<<dim3(25165824 / 1024), 256, 0, stream>>>(x, (unsigned short*)xbuf, 25165824L);
  conv_kernel<<<dim3(1769472 / 1024), 256, 0, stream>>>(qkv_w, (unsigned short*)wqkv, 1769472L);
  conv_kernel<<<dim3(589824 / 1024), 256, 0, stream>>>(proj_w, (unsigned short*)wproj, 589824L);

  // QKV projection: (32768 x 768) @ (2304 x 768)^T -> bf16 qkv
  gemm_bt_kernel<false><<<dim3(2304 / 256, 32768 / 256), 512, 0, stream>>>(
      xbuf, wqkv, qkv_b, qkv, 2304, 768);

  // pm -> bf16 (region overlaps wqkv tail: must be after gemm1)
  conv_kernel<<<dim3(16384 / 1024), 256, 0, stream>>>(pmat, (unsigned short*)pmb, 16384L);

  // kv + ksum (MFMA, m-split x L-split, no atomics; xbuf region free here)
  kv_mfma_kernel<<<dim3(96, 4, 2), 256, 0, stream>>>(qkv, pmb, kvp0, kvp1, ksp0, ksp1);

  // sum the two L-halves: kv -> bf16 kvtb, ksum in-place into ksp0
  kv_add_kernel<<<dim3(1536), 256, 0, stream>>>(kvp0, kvp1, (unsigned short*)kvtb, ksp0, ksp1);

  // q features + num/den + normalize -> bf16 attn (MFMA)
  attn_mfma_kernel<<<dim3(96, 64), 256, 0, stream>>>(qkv, pmb, kvtb, ksumb, attn);

  // output projection: (32768 x 768) @ (768 x 768)^T -> fp32 out
  gemm_bt_kernel<true><<<dim3(768 / 256, 32768 / 256), 512, 0, stream>>>(
      attn, wproj, proj_b, out, 768, 768);
}